// Round 10
// baseline (283.158 us; speedup 1.0000x reference)
//
#include <hip/hip_runtime.h>
#include <cmath>

// FlowmatchingActionHead — fp16 MFMA, algebraic collapse, W2 folded.
// R10: (1) fold_gemm reads W2 f32 ONCE, transpose+cvt in-kernel (reg-staged B),
// A1ext=[W1;b1] so b2eff = output row 64 — kills wcvt2/bias2eff/Wt2 buffer.
// (2) L3 in R4 geometry: BM64xBN128xBK64, 16 MFMA/step, ring-3 vmcnt(6).

#define NTOK 4096
#define HID  1024
#define NC   8
#define MPAD 4224

typedef _Float16 f16;
typedef _Float16 f16x8 __attribute__((ext_vector_type(8)));
typedef float    f32x4 __attribute__((ext_vector_type(4)));

#define GLDS16(g, l) __builtin_amdgcn_global_load_lds(                      \
    (const __attribute__((address_space(1))) void*)(g),                     \
    (__attribute__((address_space(3))) void*)(l), 16, 0, 0)
#define WAITV(n) asm volatile("s_waitcnt vmcnt(" #n ")" ::: "memory")

// 16B-slot index for (row r, k-chunk q) in [R][32] f16 tile (R5-verified; R<=128 ok)
__device__ __forceinline__ int slot16(int r, int q) {
  return (r >> 1) * 8 + ((((r & 1) << 2) | q) ^ ((r >> 1) & 7));
}

__global__ void build_perm_kernel(const int* __restrict__ cat,
                                  int* __restrict__ perm,
                                  int* __restrict__ cat_off,
                                  int* __restrict__ tmap) {
  __shared__ int cnt[NC];
  __shared__ int off[NC + 1];
  const int tid = threadIdx.x;
  if (tid < NC) cnt[tid] = 0;
  __syncthreads();
  for (int n = tid; n < NTOK; n += blockDim.x) atomicAdd(&cnt[cat[n]], 1);
  __syncthreads();
  if (tid == 0) {
    int s = 0;
    for (int c = 0; c < NC; ++c) { off[c] = s; s += cnt[c]; }
    off[NC] = s;
    int ns = 0;
    for (int c = 0; c < NC; ++c) {
      const int n = off[c + 1] - off[c];
      for (int m0 = 0; m0 < n; m0 += 64) tmap[1 + ns++] = (c << 20) | m0;
    }
    tmap[0] = ns;
  }
  __syncthreads();
  if (tid < NC) cnt[tid] = off[tid];
  if (tid <= NC) cat_off[tid] = off[tid];
  __syncthreads();
  for (int n = tid; n < NTOK; n += blockDim.x) {
    int pos = atomicAdd(&cnt[cat[n]], 1);
    perm[pos] = n;
  }
}

__global__ void tau16_kernel(const int* __restrict__ ts, f16* __restrict__ tau) {
  const int b = blockIdx.x;
  const float t = (float)ts[b];
  const float cdiv = -0.017988946039015984f;  // -log(10000)/512
  for (int i = threadIdx.x; i < HID / 2; i += blockDim.x) {
    float ang = t * expf(cdiv * (float)i);
    tau[(size_t)b * HID + 2 * i]     = (f16)sinf(ang);
    tau[(size_t)b * HID + 2 * i + 1] = (f16)cosf(ang);
  }
}

__global__ void gather_kernel(const float* __restrict__ actions,
                              const int* __restrict__ perm,
                              f16* __restrict__ act_g) {
  const int r = blockIdx.x;
  const int tok = perm[r];
  act_g[(size_t)r * 64 + threadIdx.x] =
      (f16)actions[(size_t)tok * 64 + threadIdx.x];
}

// A1ext (c,128,1024) f16: rows 0-63 = W1[c], row 64 = b1[c]; rows 65-127
// left poisoned (staged+MFMA'd but results discarded — finite values, safe).
__global__ void a1ext_kernel(const float* __restrict__ W1,
                             const float* __restrict__ b1,
                             f16* __restrict__ A1) {
  const int c = blockIdx.y, row = blockIdx.x;  // row 0..64
  const float* src = (row < 64) ? W1 + ((size_t)c * 64 + row) * HID
                                : b1 + (size_t)c * HID;
  f16* dst = A1 + ((size_t)c * 128 + row) * HID;
  const int i = threadIdx.x;  // 256
  float4 v = *(const float4*)(src + i * 4);
  union { f16 h[4]; uint2 u; } pk;
  pk.h[0] = (f16)v.x; pk.h[1] = (f16)v.y; pk.h[2] = (f16)v.z; pk.h[3] = (f16)v.w;
  *(uint2*)(dst + (size_t)i * 4) = pk.u;
}

// W3 (NC,K,HID) f32 -> Wt3 (NC,HID,K) f16 (verified R3-R9)
__global__ __launch_bounds__(256) void wcvt_kernel(const float* __restrict__ W,
                                                   f16* __restrict__ Wt, int K) {
  const int c = blockIdx.z, k0 = blockIdx.y * 64, n0 = blockIdx.x * 64;
  __shared__ f16 tl[64][68];
  const int tid = threadIdx.x;
  const int rr = tid >> 4, cs = (tid & 15) * 4;
  const float* src = W + ((size_t)c * K + k0) * HID + n0;
#pragma unroll
  for (int it = 0; it < 4; ++it) {
    const int kr = rr + it * 16;
    float4 v = *(const float4*)(src + (size_t)kr * HID + cs);
    tl[kr][cs + 0] = (f16)v.x;
    tl[kr][cs + 1] = (f16)v.y;
    tl[kr][cs + 2] = (f16)v.z;
    tl[kr][cs + 3] = (f16)v.w;
  }
  __syncthreads();
  f16* dst = Wt + ((size_t)c * HID + n0) * K + k0;
#pragma unroll
  for (int it = 0; it < 4; ++it) {
    const int nr = rr + it * 16;
    union { f16 h[4]; uint2 u; } pk;
    pk.h[0] = tl[cs + 0][nr];
    pk.h[1] = tl[cs + 1][nr];
    pk.h[2] = tl[cs + 2][nr];
    pk.h[3] = tl[cs + 3][nr];
    *(uint2*)(dst + (size_t)nr * K + cs) = pk.u;
  }
}

// fold_gemm: M=128, N=64, K=1024, BK=32. A f16 via GLDS16; B from W2 f32,
// reg-staged transpose+convert (issue-early/write-late, 1 barrier/step).
// MODE 0: A=A1ext[c]; C rows 0-63 -> W12t[c][o][a], row 64 -> b2eff[c][o].
// MODE 1: A=tau16;    C rows 0-127 -> ttau[c][b][o] (+ b2eff + b2).
template <int MODE>
__global__ __launch_bounds__(256, 4) void fold_gemm(
    const f16* __restrict__ A, const float* __restrict__ W2,
    const float* __restrict__ b2, float* __restrict__ b2eff,
    f16* __restrict__ W12t, float* __restrict__ ttau) {
  constexpr int NT = 32;
  const int c = blockIdx.y;
  const int n0 = blockIdx.x * 64;

  __shared__ f16 As[2][128 * 32];
  __shared__ f16 Bs[2][64 * 32];

  const int tid = threadIdx.x;
  const int lane = tid & 63, wid = tid >> 6;
  const int fr = lane & 15, fq = lane >> 4;

  const f16* Abase = (MODE == 0) ? A + (size_t)c * 131072 : A;
  const float* Wbase = W2 + (size_t)c * 2097152 +
                       (MODE == 0 ? (size_t)0 : (size_t)1024 * HID) + n0;

  // A slots: 2/thread over 512 (inverse pair-XOR swizzle, R5 construction)
  int asr[2], asq[2], asl[2];
#pragma unroll
  for (int i = 0; i < 2; ++i) {
    const int s = tid + i * 256;
    const int pr = s >> 3, u = s & 7, w = u ^ (pr & 7);
    asr[i] = 2 * pr + (w >> 2); asq[i] = (w & 3) * 8; asl[i] = s * 8;
  }
  // B: 2 float4/thread = (o-quad, m)
  int bo4[2], bm[2];
#pragma unroll
  for (int r = 0; r < 2; ++r) {
    const int g = r * 256 + tid;
    bo4[r] = (g & 15) * 4; bm[r] = g >> 4;
  }
  float4 breg[2];

#define ISSUE_A(buf, kt)                                                     \
  do {                                                                       \
    _Pragma("unroll") for (int i_ = 0; i_ < 2; ++i_)                         \
      GLDS16(Abase + (size_t)asr[i_] * HID + (kt) + asq[i_],                 \
             &As[buf][asl[i_]]);                                             \
  } while (0)
#define LOAD_B(kt)                                                           \
  do {                                                                       \
    _Pragma("unroll") for (int r_ = 0; r_ < 2; ++r_)                         \
      breg[r_] = *(const float4*)(Wbase + (size_t)(bm[r_] + (kt)) * HID +    \
                                  bo4[r_]);                                  \
  } while (0)
#define WRITE_B(buf)                                                         \
  do {                                                                       \
    _Pragma("unroll") for (int r_ = 0; r_ < 2; ++r_) {                       \
      const float* f_ = (const float*)&breg[r_];                             \
      _Pragma("unroll") for (int i_ = 0; i_ < 4; ++i_)                       \
        Bs[buf][slot16(bo4[r_] + i_, bm[r_] >> 3) * 8 + (bm[r_] & 7)] =      \
            (f16)f_[i_];                                                     \
    }                                                                        \
  } while (0)

  f32x4 acc[2][4];
#pragma unroll
  for (int i = 0; i < 2; ++i)
#pragma unroll
    for (int j = 0; j < 4; ++j) acc[i][j] = (f32x4){0.f, 0.f, 0.f, 0.f};

  ISSUE_A(0, 0); LOAD_B(0);
  WAITV(0);
  WRITE_B(0);
  __syncthreads();

  for (int t = 0; t < NT; ++t) {
    const int cur = t & 1;
    if (t + 1 < NT) { ISSUE_A(cur ^ 1, (t + 1) * 32); LOAD_B((t + 1) * 32); }
    f16x8 a0 = *(const f16x8*)&As[cur][slot16(wid * 16 + fr, fq) * 8];
    f16x8 a1 = *(const f16x8*)&As[cur][slot16(64 + wid * 16 + fr, fq) * 8];
    f16x8 bf[4];
#pragma unroll
    for (int j = 0; j < 4; ++j)
      bf[j] = *(const f16x8*)&Bs[cur][slot16(j * 16 + fr, fq) * 8];
#pragma unroll
    for (int j = 0; j < 4; ++j) {
      acc[0][j] = __builtin_amdgcn_mfma_f32_16x16x32_f16(a0, bf[j], acc[0][j], 0, 0, 0);
      acc[1][j] = __builtin_amdgcn_mfma_f32_16x16x32_f16(a1, bf[j], acc[1][j], 0, 0, 0);
    }
    if (t + 1 < NT) { WAITV(0); WRITE_B(cur ^ 1); }
    __syncthreads();
  }
#undef ISSUE_A
#undef LOAD_B
#undef WRITE_B

#pragma unroll
  for (int j = 0; j < 4; ++j) {
    const int col = j * 16 + fr, o = n0 + col;
#pragma unroll
    for (int q = 0; q < 4; ++q) {
      const int row0 = wid * 16 + fq * 4 + q;
      if constexpr (MODE == 0) {
        W12t[(size_t)c * 65536 + (size_t)o * 64 + row0] = (f16)acc[0][j][q];
        if (wid == 0 && fq == 0 && q == 0)
          b2eff[c * HID + o] = acc[1][j][q];  // A row 64 = b1 -> b1@W2top
      } else {
        const float bb = b2eff[c * HID + o] + b2[c * HID + o];
        ttau[(size_t)c * 131072 + (size_t)row0 * HID + o] = acc[0][j][q] + bb;
        ttau[(size_t)c * 131072 + (size_t)(64 + row0) * HID + o] = acc[1][j][q] + bb;
      }
    }
  }
}

// L2PRE: h = silu(act_g @ W12t + ttau[tok&127])  (K=64, R9-verified machinery)
__global__ __launch_bounds__(256, 4) void l2pre_gemm(
    const f16* __restrict__ A, const f16* __restrict__ B,
    const float* __restrict__ Ttau, const int* __restrict__ perm,
    const int* __restrict__ cat_off, const int* __restrict__ tmap,
    f16* __restrict__ H) {
  constexpr int NT = 2;
  const int nslots = tmap[0];
  if ((int)blockIdx.y >= nslots) return;
  const int ent = tmap[1 + blockIdx.y];
  const int c = ent >> 20, m0 = ent & 0xFFF;
  const int g0 = cat_off[c], cnt = cat_off[c + 1] - g0;
  const int n0 = blockIdx.x * 64;

  __shared__ f16 As[2][64 * 32];
  __shared__ f16 Bs[2][64 * 32];
  __shared__ int rows[64];

  const int tid = threadIdx.x;
  const int lane = tid & 63, wid = tid >> 6;
  const int fr = lane & 15, fq = lane >> 4;

  if (tid < 64) {
    int m = m0 + tid;
    if (m > cnt - 1) m = cnt - 1;
    rows[tid] = perm[g0 + m];
  }

  const f16* Abase = A + (size_t)(g0 + m0) * 64;
  const f16* Bbase = B + (size_t)c * 65536 + (size_t)n0 * 64;

  const int pr_ = tid >> 3, u_ = tid & 7, w_ = u_ ^ (pr_ & 7);
  const int sr_ = 2 * pr_ + (w_ >> 2), sq_ = (w_ & 3) * 8;
#define STAGE(buf, kt)                                                   \
  do {                                                                   \
    GLDS16(Abase + (size_t)sr_ * 64 + (kt) + sq_, &As[buf][tid * 8]);    \
    GLDS16(Bbase + (size_t)sr_ * 64 + (kt) + sq_, &Bs[buf][tid * 8]);    \
  } while (0)

  f32x4 acc[4];
#pragma unroll
  for (int j = 0; j < 4; ++j) acc[j] = (f32x4){0.f, 0.f, 0.f, 0.f};

  STAGE(0, 0);
  STAGE(1, 32);
  for (int t = 0; t < NT; ++t) {
    if (t + 1 < NT) { WAITV(2); } else { WAITV(0); }
    __builtin_amdgcn_s_barrier();
    const int cur = t & 1;
    const int ar = wid * 16 + fr;
    f16x8 af = *(const f16x8*)&As[cur][slot16(ar, fq) * 8];
    f16x8 bf[4];
#pragma unroll
    for (int j = 0; j < 4; ++j)
      bf[j] = *(const f16x8*)&Bs[cur][slot16(j * 16 + fr, fq) * 8];
#pragma unroll
    for (int j = 0; j < 4; ++j)
      acc[j] = __builtin_amdgcn_mfma_f32_16x16x32_f16(af, bf[j], acc[j], 0, 0, 0);
  }
#undef STAGE

  const int mlb = wid * 16 + fq * 4;
#pragma unroll
  for (int j = 0; j < 4; ++j) {
    const int col = j * 16 + fr;
#pragma unroll
    for (int q = 0; q < 4; ++q) {
      const int ml = mlb + q;
      if (m0 + ml >= cnt) continue;
      const int b = rows[ml] & 127;
      float v = acc[j][q] + Ttau[((size_t)c * 128 + b) * HID + n0 + col];
      v = v / (1.0f + __expf(-v));
      H[(size_t)(g0 + m0 + ml) * HID + n0 + col] = (f16)v;
    }
  }
}

// L3: out = h @ Wt3 + b3, scattered. R4 geometry: BM64 BN128 BK64, ring-3,
// counted vmcnt(6), row-XOR swizzle (R4-verified: 0 conflicts, correct).
__global__ __launch_bounds__(256, 2) void l3_gemm(
    const f16* __restrict__ A, const f16* __restrict__ Wt,
    const float* __restrict__ Bias, const int* __restrict__ perm,
    const int* __restrict__ cat_off, const int* __restrict__ tmap,
    float* __restrict__ Out) {
  constexpr int BK = 64, NT = 1024 / BK;  // 16
  const int nslots = tmap[0];
  if ((int)blockIdx.y >= nslots) return;
  const int ent = tmap[1 + blockIdx.y];
  const int c = ent >> 20, m0 = ent & 0xFFF;
  const int g0 = cat_off[c], cnt = cat_off[c + 1] - g0;
  const int n0 = blockIdx.x * 128;

  __shared__ f16 As[3][64 * BK];   // 3 x 8 KiB
  __shared__ f16 Bs[3][128 * BK];  // 3 x 16 KiB
  __shared__ int rows[64];

  const int tid = threadIdx.x;
  const int lane = tid & 63, wid = tid >> 6;
  const int wm = wid >> 1, wn = wid & 1;
  const int fr = lane & 15, fq = lane >> 4;

  if (tid < 64) {
    int m = m0 + tid;
    if (m > cnt - 1) m = cnt - 1;
    rows[tid] = perm[g0 + m];
  }

  const f16* Abase = A + (size_t)(g0 + m0) * HID;
  const f16* Bbase = Wt + ((size_t)c * HID + n0) * HID;

#define STAGE(buf, kt)                                                        \
  do {                                                                        \
    _Pragma("unroll") for (int i_ = 0; i_ < 2; ++i_) {                        \
      const int s_ = tid + i_ * 256;                                          \
      const int r_ = s_ >> 3, qg_ = (s_ & 7) ^ (r_ & 7);                      \
      GLDS16(Abase + (size_t)r_ * HID + (kt) + qg_ * 8, &As[buf][s_ * 8]);    \
    }                                                                         \
    _Pragma("unroll") for (int i_ = 0; i_ < 4; ++i_) {                        \
      const int s_ = tid + i_ * 256;                                          \
      const int r_ = s_ >> 3, qg_ = (s_ & 7) ^ (r_ & 7);                      \
      GLDS16(Bbase + (size_t)r_ * HID + (kt) + qg_ * 8, &Bs[buf][s_ * 8]);    \
    }                                                                         \
  } while (0)

  f32x4 acc[2][4];
#pragma unroll
  for (int i = 0; i < 2; ++i)
#pragma unroll
    for (int j = 0; j < 4; ++j) acc[i][j] = (f32x4){0.f, 0.f, 0.f, 0.f};

  STAGE(0, 0);
  STAGE(1, BK);

  for (int t = 0; t < NT; ++t) {
    if (t + 1 < NT) { WAITV(6); } else { WAITV(0); }
    __builtin_amdgcn_s_barrier();
    const int cur = t % 3;

    f16x8 af[2][2], bf[2][4];
#pragma unroll
    for (int ks = 0; ks < 2; ++ks) {
      const int q = ks * 4 + fq;
#pragma unroll
      for (int i = 0; i < 2; ++i) {
        const int r = wm * 32 + i * 16 + fr;
        af[ks][i] = *(const f16x8*)&As[cur][r * 64 + ((q ^ (r & 7)) * 8)];
      }
#pragma unroll
      for (int j = 0; j < 4; ++j) {
        const int r = wn * 64 + j * 16 + fr;
        bf[ks][j] = *(const f16x8*)&Bs[cur][r * 64 + ((q ^ (r & 7)) * 8)];
      }
    }
#pragma unroll
    for (int ks = 0; ks < 2; ++ks)
#pragma unroll
      for (int i = 0; i < 2; ++i)
#pragma unroll
        for (int j = 0; j < 4; ++j)
          acc[i][j] = __builtin_amdgcn_mfma_f32_16x16x32_f16(af[ks][i], bf[ks][j],
                                                             acc[i][j], 0, 0, 0);
    if (t + 2 < NT) STAGE((t + 2) % 3, (t + 2) * BK);
  }
#undef STAGE

#pragma unroll
  for (int i = 0; i < 2; ++i) {
    const int mlb = wm * 32 + i * 16 + fq * 4;
#pragma unroll
    for (int j = 0; j < 4; ++j) {
      const int col = wn * 64 + j * 16 + fr;
      const float bb = Bias[c * HID + n0 + col];
#pragma unroll
      for (int q = 0; q < 4; ++q) {
        const int ml = mlb + q;
        if (m0 + ml >= cnt) continue;
        Out[(size_t)rows[ml] * HID + n0 + col] = acc[i][j][q] + bb;
      }
    }
  }
}

extern "C" void kernel_launch(void* const* d_in, const int* in_sizes, int n_in,
                              void* d_out, int out_size, void* d_ws, size_t ws_size,
                              hipStream_t stream) {
  const float* actions   = (const float*)d_in[0];
  const int*   timesteps = (const int*)d_in[1];
  const int*   cat_ids   = (const int*)d_in[2];
  const float* W1 = (const float*)d_in[3];
  const float* b1 = (const float*)d_in[4];
  const float* W2 = (const float*)d_in[5];
  const float* b2 = (const float*)d_in[6];
  const float* W3 = (const float*)d_in[7];
  const float* b3 = (const float*)d_in[8];
  float* out = (float*)d_out;

  char* ws = (char*)d_ws;
  const size_t MiB = 1u << 20;
  int*   perm    = (int*)(ws + 0);                 // 16 KiB
  int*   cat_off = (int*)(ws + (16u << 10));       // 64 B
  int*   tmap    = (int*)(ws + (20u << 10));       // 512 B
  f16*   tau16   = (f16*)(ws + (32u << 10));       // 256 KiB (128x1024)
  f16*   act_g   = (f16*)(ws + (512u << 10));      // 528 KiB (MPADx64)
  f16*   A1ext   = (f16*)(ws + 2 * MiB);           // 2 MiB (8,128,1024)
  f16*   W12t    = (f16*)(ws + 4 * MiB);           // 1 MiB (8,1024,64)
  float* b2eff   = (float*)(ws + 5 * MiB);         // 32 KiB (8,1024)
  float* ttau    = (float*)(ws + 6 * MiB);         // 4 MiB (8,128,1024)
  f16*   h       = (f16*)(ws + 10 * MiB);          // 8.25 MiB (MPADx1024)
  f16*   Wt3     = (f16*)(ws + 19 * MiB);          // 16 MiB -> ends 35 MiB

  build_perm_kernel<<<1, 1024, 0, stream>>>(cat_ids, perm, cat_off, tmap);
  tau16_kernel<<<128, 256, 0, stream>>>(timesteps, tau16);
  gather_kernel<<<NTOK, 64, 0, stream>>>(actions, perm, act_g);
  a1ext_kernel<<<dim3(65, NC), 256, 0, stream>>>(W1, b1, A1ext);
  wcvt_kernel<<<dim3(HID / 64, 16, NC), 256, 0, stream>>>(W3, Wt3, 1024);

  // W12B: W12t[c][o][a] = (W1@W2top)^T; row64 -> b2eff = b1@W2top
  fold_gemm<0><<<dim3(16, NC), 256, 0, stream>>>(A1ext, W2, nullptr, b2eff,
                                                 W12t, nullptr);
  // TTAU: ttau[c][b][o] = tau@W2bot + b2eff + b2
  fold_gemm<1><<<dim3(16, NC), 256, 0, stream>>>(tau16, W2, b2, b2eff,
                                                 nullptr, ttau);
  // L2PRE: h = silu(act_g @ W12t + ttau[row])  (K=64)
  l2pre_gemm<<<dim3(16, 72), 256, 0, stream>>>(act_g, W12t, ttau, perm,
                                               cat_off, tmap, h);
  // L3: out = h @ Wt3 + b3, scattered
  l3_gemm<<<dim3(8, 72), 256, 0, stream>>>(h, Wt3, b3, perm, cat_off, tmap, out);
}